// Round 4
// baseline (654.440 us; speedup 1.0000x reference)
//
#include <hip/hip_runtime.h>
#include <math.h>

#define DMODEL 512
#define NHEADS 8
#define NEXP 4
#define SEQ 1024
#define BATCH 4
#define NTOK 4096  // BATCH * SEQ

typedef float v2f __attribute__((ext_vector_type(2)));
typedef float v4f __attribute__((ext_vector_type(4)));

__device__ __forceinline__ float dev_sigmoid(float x) { return 1.0f / (1.0f + expf(-x)); }
__device__ __forceinline__ float dev_silu(float x) { return x / (1.0f + expf(-x)); }
__device__ __forceinline__ float dev_softplus(float x) {
  return x > 0.0f ? x + log1pf(expf(-x)) : log1pf(expf(x));
}

// ---------------- zero kernel (core accumulator must start at 0; ws is poisoned 0xAA) ----
__global__ __launch_bounds__(256) void zero_kernel(float4* __restrict__ p) {
  p[(size_t)blockIdx.x * 256 + threadIdx.x] = make_float4(0.f, 0.f, 0.f, 0.f);
}

// ---------------- router + beta/g small projections: one wave per token ----------------
__global__ __launch_bounds__(64) void router_kernel(
    const float* __restrict__ h, const float* __restrict__ Wb,
    const float* __restrict__ Wa, const float* __restrict__ Wgate,
    const float* __restrict__ A_log, const float* __restrict__ dt_bias,
    float* __restrict__ beta_o, float* __restrict__ g_o, float* __restrict__ w_o) {
  const int t = blockIdx.x;
  const int lane = threadIdx.x;
  float hv[8];
#pragma unroll
  for (int j = 0; j < 8; ++j) hv[j] = h[(size_t)t * DMODEL + j * 64 + lane];
  float db[8], da[8], dg[4];
#pragma unroll
  for (int c = 0; c < 8; ++c) {
    float s1 = 0.f, s2 = 0.f;
#pragma unroll
    for (int j = 0; j < 8; ++j) {
      int row = j * 64 + lane;
      s1 += hv[j] * Wb[row * NHEADS + c];
      s2 += hv[j] * Wa[row * NHEADS + c];
    }
#pragma unroll
    for (int off = 1; off < 64; off <<= 1) {
      s1 += __shfl_xor(s1, off);
      s2 += __shfl_xor(s2, off);
    }
    db[c] = s1; da[c] = s2;
  }
#pragma unroll
  for (int c = 0; c < 4; ++c) {
    float s = 0.f;
#pragma unroll
    for (int j = 0; j < 8; ++j) s += hv[j] * Wgate[(j * 64 + lane) * NEXP + c];
#pragma unroll
    for (int off = 1; off < 64; off <<= 1) s += __shfl_xor(s, off);
    dg[c] = s;
  }
  if (lane == 0) {
#pragma unroll
    for (int c = 0; c < 8; ++c) {
      beta_o[t * NHEADS + c] = dev_sigmoid(db[c]);
      g_o[t * NHEADS + c] = -expf(A_log[c]) * dev_softplus(da[c] + dt_bias[c]);
    }
    // softmax over 4 experts (max-subtracted, like jax.nn.softmax)
    float mx = fmaxf(fmaxf(dg[0], dg[1]), fmaxf(dg[2], dg[3]));
    float p[4]; float sum = 0.f;
#pragma unroll
    for (int c = 0; c < 4; ++c) { p[c] = expf(dg[c] - mx); sum += p[c]; }
#pragma unroll
    for (int c = 0; c < 4; ++c) p[c] /= sum;
    // top-2, first-occurrence tie-break (matches jax.lax.top_k)
    float v1 = -1e30f; int i1 = 0;
#pragma unroll
    for (int c = 0; c < 4; ++c) { if (p[c] > v1) { v1 = p[c]; i1 = c; } }
    float v2 = -1e30f; int i2 = -1;
#pragma unroll
    for (int c = 0; c < 4; ++c) { if (c != i1 && p[c] > v2) { v2 = p[c]; i2 = c; } }
    float s2v = v1 + v2;
#pragma unroll
    for (int c = 0; c < 4; ++c) {
      float wv = 0.f;
      if (c == i1) wv = v1 / s2v;
      else if (c == i2) wv = v2 / s2v;
      w_o[t * NEXP + c] = wv;
    }
  }
}

// ---------------- fp32 tiled GEMM: C[M,512] = A[M,512] @ B[512,512] -----------------
// MODE 0: plain   MODE 1: silu   MODE 2: silu + per-64-col-head l2norm
template <int MODE>
__global__ __launch_bounds__(256) void gemm512(
    const float* __restrict__ A, const float* __restrict__ B,
    float* __restrict__ C) {
  constexpr int N = DMODEL, K = DMODEL;
  __shared__ float As[32][68];  // [k][m], padded
  __shared__ float Bs[32][68];  // [k][n], padded
  const int tid = threadIdx.x;
  const int tx = tid & 15, ty = tid >> 4;
  const int m0 = blockIdx.x * 64, n0 = blockIdx.y * 64;
  const int ar = tid >> 3, ak = (tid & 7) * 4;
  const int bk = tid >> 4, bn = (tid & 15) * 4;
  float acc[4][4] = {};
  for (int kk = 0; kk < K; kk += 32) {
    float4 a0 = *(const float4*)&A[(size_t)(m0 + ar) * K + kk + ak];
    float4 a1 = *(const float4*)&A[(size_t)(m0 + ar + 32) * K + kk + ak];
    float4 b0 = *(const float4*)&B[(size_t)(kk + bk) * N + n0 + bn];
    float4 b1 = *(const float4*)&B[(size_t)(kk + bk + 16) * N + n0 + bn];
    __syncthreads();
    As[ak + 0][ar] = a0.x; As[ak + 1][ar] = a0.y; As[ak + 2][ar] = a0.z; As[ak + 3][ar] = a0.w;
    As[ak + 0][ar + 32] = a1.x; As[ak + 1][ar + 32] = a1.y; As[ak + 2][ar + 32] = a1.z; As[ak + 3][ar + 32] = a1.w;
    *(float4*)&Bs[bk][bn] = b0;
    *(float4*)&Bs[bk + 16][bn] = b1;
    __syncthreads();
#pragma unroll
    for (int kq = 0; kq < 32; ++kq) {
      float4 a4 = *(const float4*)&As[kq][ty * 4];
      float4 b4 = *(const float4*)&Bs[kq][tx * 4];
      float av[4] = {a4.x, a4.y, a4.z, a4.w};
      float bv[4] = {b4.x, b4.y, b4.z, b4.w};
#pragma unroll
      for (int i = 0; i < 4; ++i)
#pragma unroll
        for (int j = 0; j < 4; ++j) acc[i][j] = fmaf(av[i], bv[j], acc[i][j]);
    }
  }
  if (MODE == 0) {
#pragma unroll
    for (int i = 0; i < 4; ++i) {
      float4 v4 = make_float4(acc[i][0], acc[i][1], acc[i][2], acc[i][3]);
      *(float4*)&C[(size_t)(m0 + ty * 4 + i) * N + n0 + tx * 4] = v4;
    }
  } else {
    float s[4][4];
#pragma unroll
    for (int i = 0; i < 4; ++i)
#pragma unroll
      for (int j = 0; j < 4; ++j) s[i][j] = dev_silu(acc[i][j]);
    if (MODE == 2) {
      // l2norm over the 64 cols of this head (tile == head): reduce across the 16 tx lanes
      float ss[4];
#pragma unroll
      for (int i = 0; i < 4; ++i)
        ss[i] = s[i][0] * s[i][0] + s[i][1] * s[i][1] + s[i][2] * s[i][2] + s[i][3] * s[i][3];
#pragma unroll
      for (int off = 1; off < 16; off <<= 1) {
#pragma unroll
        for (int i = 0; i < 4; ++i) ss[i] += __shfl_xor(ss[i], off);
      }
#pragma unroll
      for (int i = 0; i < 4; ++i) {
        float rn = 1.0f / sqrtf(ss[i] + 1e-6f);
#pragma unroll
        for (int j = 0; j < 4; ++j) s[i][j] *= rn;
      }
    }
#pragma unroll
    for (int i = 0; i < 4; ++i) {
      float4 v4 = make_float4(s[i][0], s[i][1], s[i][2], s[i][3]);
      *(float4*)&C[(size_t)(m0 + ty * 4 + i) * N + n0 + tx * 4] = v4;
    }
  }
}

// ---------------- gated delta-rule scan ----------------
// grid (NEXP*2, BATCH, NHEADS); ONE WAVE per block.
// NO token compaction: all SEQ steps, affine forward-streaming addresses.
// Non-routed steps (w==0) leave S unchanged (beta=0,g=0) -> wave-uniform skip
// of the compute body; the prefetch/stage pipeline advances unconditionally.
// vhalf = blockIdx.x&1 selects 32 of the 64 v-columns; lane = (kh, vi).
// Depth-6 software pipeline over 8 rotating slots:
//   step s: issue global loads for s+6; compute s (LDS staged at s-1);
//           stage LDS for s+1 (regs loaded at s-5).
// Iteration order: prefetch -> compute ds_reads -> stage ds_writes, so reads
// never queue behind same-step writes in the in-order DS pipe.
__global__ __launch_bounds__(64) void scan_kernel(
    const float* __restrict__ qb, const float* __restrict__ kb,
    const float* __restrict__ vb, const float* __restrict__ betab,
    const float* __restrict__ gbuf, const float* __restrict__ wbuf,
    float* __restrict__ coreb) {
  const int vhalf = blockIdx.x & 1, e = blockIdx.x >> 1;
  const int b = blockIdx.y, hh = blockIdx.z;
  const int lane = threadIdx.x;
  const int kh = lane >> 5;
  const int vi = lane & 31;
  const int cv = vhalf * 32 + vi;
  const size_t hoff = (size_t)hh * 64;

  __shared__ __align__(16) float lk[8][64];
  __shared__ __align__(16) float lq[8][64];

  v2f S2[16];
#pragma unroll
  for (int j = 0; j < 16; ++j) S2[j] = (v2f){0.f, 0.f};

  float kf[8], qf[8], vf[8], gf[8], bf[8], wf[8];

#define PREF(SLOT, L)                                                 \
  do {                                                                \
    const int l_ = (L) < SEQ ? (L) : (SEQ - 1);                       \
    const int t_ = b * SEQ + l_;                                      \
    const size_t ro_ = (size_t)t_ * DMODEL + hoff;                    \
    kf[SLOT] = kb[ro_ + lane];                                        \
    qf[SLOT] = qb[ro_ + lane];                                        \
    vf[SLOT] = vb[ro_ + cv];                                          \
    gf[SLOT] = gbuf[t_ * NHEADS + hh];                                \
    bf[SLOT] = betab[t_ * NHEADS + hh];                               \
    wf[SLOT] = wbuf[t_ * NEXP + e];                                   \
  } while (0)

  // prologue: loads for steps 0..5; stage step 0
  PREF(0, 0); PREF(1, 1); PREF(2, 2); PREF(3, 3); PREF(4, 4); PREF(5, 5);
  lk[0][lane] = kf[0];
  lq[0][lane] = qf[0];

  for (int i = 0; i < SEQ; i += 8) {
#pragma unroll
    for (int u = 0; u < 8; ++u) {
      const int s = i + u;
      // 1. issue global loads for step s+6 (slot was freed at step s-2)
      PREF((u + 6) & 7, s + 6);
      // 2. compute step s from LDS slot u (staged at step s-1)
      const float wcur = wf[u];
      if (wcur > 0.f) {
        const v4f* K4 = (const v4f*)&lk[u][kh * 32];
        const v4f* Q4 = (const v4f*)&lq[u][kh * 32];
        v2f myk[16];
        v2f c0 = (v2f){0.f, 0.f}, c1 = c0, c2 = c0, c3 = c0;
#pragma unroll
        for (int j = 0; j < 8; ++j) {
          const v4f k4 = K4[j];
          const v2f klo = (v2f){k4.x, k4.y};
          const v2f khi = (v2f){k4.z, k4.w};
          myk[2 * j] = klo; myk[2 * j + 1] = khi;
          if (j & 1) {
            c2 = __builtin_elementwise_fma(klo, S2[2 * j], c2);
            c3 = __builtin_elementwise_fma(khi, S2[2 * j + 1], c3);
          } else {
            c0 = __builtin_elementwise_fma(klo, S2[2 * j], c0);
            c1 = __builtin_elementwise_fma(khi, S2[2 * j + 1], c1);
          }
        }
        const v2f cacc = (c0 + c1) + (c2 + c3);
        float c = cacc.x + cacc.y;
        c += __shfl_xor(c, 32);  // combine k-halves
        const float egc = expf(gf[u]);
        const float delta = (vf[u] - egc * c) * bf[u];
        const v2f d2 = (v2f){delta, delta};
        const v2f eg2 = (v2f){egc, egc};
        v2f o0 = (v2f){0.f, 0.f}, o1 = o0, o2 = o0, o3 = o0;
#pragma unroll
        for (int j = 0; j < 8; ++j) {
          const v4f q4 = Q4[j];
          const v2f qlo = (v2f){q4.x, q4.y};
          const v2f qhi = (v2f){q4.z, q4.w};
          const v2f s0 = __builtin_elementwise_fma(S2[2 * j], eg2, myk[2 * j] * d2);
          const v2f s1v = __builtin_elementwise_fma(S2[2 * j + 1], eg2, myk[2 * j + 1] * d2);
          S2[2 * j] = s0; S2[2 * j + 1] = s1v;
          if (j & 1) {
            o2 = __builtin_elementwise_fma(qlo, s0, o2);
            o3 = __builtin_elementwise_fma(qhi, s1v, o3);
          } else {
            o0 = __builtin_elementwise_fma(qlo, s0, o0);
            o1 = __builtin_elementwise_fma(qhi, s1v, o1);
          }
        }
        const v2f oacc = (o0 + o1) + (o2 + o3);
        float o = oacc.x + oacc.y;
        o += __shfl_xor(o, 32);
        if (kh == 0)
          atomicAdd(&coreb[(size_t)(b * SEQ + s) * DMODEL + hoff + cv],
                    o * 0.125f * wcur);
      }
      // 3. stage LDS for step s+1 from regs loaded at step s-5
      const int s1 = (u + 1) & 7;
      __builtin_amdgcn_wave_barrier();
      lk[s1][lane] = kf[s1];
      lq[s1][lane] = qf[s1];
      __builtin_amdgcn_wave_barrier();
    }
  }
#undef PREF
}

// ---------------- fused gated RMSNorm: one wave per (token, head) ----------------
__global__ __launch_bounds__(512) void rmsnorm_kernel(
    const float* __restrict__ coreb, const float* __restrict__ gateb,
    const float* __restrict__ wn, float* __restrict__ outb) {
  const int t = blockIdx.x;
  const int tid = threadIdx.x;  // 512 = 8 heads * 64; wave == head
  const int v = tid & 63;
  const float x = coreb[(size_t)t * DMODEL + tid];
  float ss = x * x;
#pragma unroll
  for (int off = 1; off < 64; off <<= 1) ss += __shfl_xor(ss, off);
  const float r = rsqrtf(ss * (1.0f / 64.0f) + 1e-5f);
  const float gt = gateb[(size_t)t * DMODEL + tid];  // already silu'd
  outb[(size_t)t * DMODEL + tid] = x * r * wn[v] * gt;
}

extern "C" void kernel_launch(void* const* d_in, const int* in_sizes, int n_in,
                              void* d_out, int out_size, void* d_ws, size_t ws_size,
                              hipStream_t stream) {
  const float* h       = (const float*)d_in[0];
  const float* Wq      = (const float*)d_in[1];
  const float* Wgate   = (const float*)d_in[2];
  const float* Wk      = (const float*)d_in[3];
  const float* Wv      = (const float*)d_in[4];
  const float* Wb      = (const float*)d_in[5];
  const float* Wa      = (const float*)d_in[6];
  const float* A_log   = (const float*)d_in[7];
  const float* dt_bias = (const float*)d_in[8];
  const float* Wg      = (const float*)d_in[9];
  const float* wn      = (const float*)d_in[10];
  const float* Wo      = (const float*)d_in[11];
  float* out = (float*)d_out;

  float* ws = (float*)d_ws;
  const size_t big = (size_t)NTOK * DMODEL;  // 2M floats
  float* qb    = ws;
  float* kb    = qb + big;
  float* vb    = kb + big;
  float* gateb = vb + big;
  float* coreb = gateb + big;
  float* betab = coreb + big;
  float* gbuf  = betab + (size_t)NTOK * NHEADS;
  float* wbuf  = gbuf + (size_t)NTOK * NHEADS;
  float* normb = qb;  // reuse q buffer after the scan

  // zero the core accumulator (ws is poisoned before every timed launch)
  zero_kernel<<<dim3(NTOK * DMODEL / 4 / 256), 256, 0, stream>>>((float4*)coreb);

  router_kernel<<<dim3(NTOK), 64, 0, stream>>>(h, Wb, Wa, Wgate, A_log, dt_bias,
                                               betab, gbuf, wbuf);

  dim3 gg(NTOK / 64, DMODEL / 64);
  gemm512<2><<<gg, 256, 0, stream>>>(h, Wq, qb);
  gemm512<2><<<gg, 256, 0, stream>>>(h, Wk, kb);
  gemm512<1><<<gg, 256, 0, stream>>>(h, Wv, vb);
  gemm512<1><<<gg, 256, 0, stream>>>(h, Wg, gateb);

  scan_kernel<<<dim3(NEXP * 2, BATCH, NHEADS), 64, 0, stream>>>(
      qb, kb, vb, betab, gbuf, wbuf, coreb);

  rmsnorm_kernel<<<dim3(NTOK), 512, 0, stream>>>(coreb, gateb, wn, normb);

  gemm512<0><<<gg, 256, 0, stream>>>(normb, Wo, out);
}

// Round 5
// 499.125 us; speedup vs baseline: 1.3112x; 1.3112x over previous
//
#include <hip/hip_runtime.h>
#include <math.h>

#define DMODEL 512
#define NHEADS 8
#define NEXP 4
#define SEQ 1024
#define BATCH 4
#define NTOK 4096  // BATCH * SEQ

typedef float v2f __attribute__((ext_vector_type(2)));
typedef float v4f __attribute__((ext_vector_type(4)));
typedef short bf16x8 __attribute__((ext_vector_type(8)));
typedef float f32x4 __attribute__((ext_vector_type(4)));
typedef unsigned short u16;

__device__ __forceinline__ float dev_sigmoid(float x) { return 1.0f / (1.0f + expf(-x)); }
__device__ __forceinline__ float dev_silu(float x) { return x / (1.0f + expf(-x)); }
__device__ __forceinline__ float dev_softplus(float x) {
  return x > 0.0f ? x + log1pf(expf(-x)) : log1pf(expf(x));
}
// fp32 -> bf16 bits, round-to-nearest-even
__device__ __forceinline__ u16 f2b(float f) {
  unsigned int u = __float_as_uint(f);
  unsigned int r = (u + 0x7fffu + ((u >> 16) & 1u)) >> 16;
  return (u16)r;
}

// ---------------- zero kernel (core accumulator must start at 0; ws is poisoned 0xAA) ----
__global__ __launch_bounds__(256) void zero_kernel(float4* __restrict__ p) {
  p[(size_t)blockIdx.x * 256 + threadIdx.x] = make_float4(0.f, 0.f, 0.f, 0.f);
}

// ---------------- cast h (fp32) -> bf16 bits ----------------
__global__ __launch_bounds__(256) void cast_h_kernel(const float4* __restrict__ in,
                                                     ushort4* __restrict__ outp) {
  const size_t i = (size_t)blockIdx.x * 256 + threadIdx.x;
  float4 v = in[i];
  ushort4 o;
  o.x = f2b(v.x); o.y = f2b(v.y); o.z = f2b(v.z); o.w = f2b(v.w);
  outp[i] = o;
}

// ---------------- transpose-cast weight: W[512][512] fp32 -> Wt[n][k] bf16 ----------------
__global__ __launch_bounds__(256) void castT_kernel(const float* __restrict__ in,
                                                    u16* __restrict__ outp) {
  __shared__ float tile[32][33];
  const int bx = blockIdx.x * 32;  // k base
  const int by = blockIdx.y * 32;  // n base
  const int c = threadIdx.x & 31, r0 = threadIdx.x >> 5;
#pragma unroll
  for (int r = r0; r < 32; r += 8) tile[r][c] = in[(size_t)(bx + r) * DMODEL + by + c];
  __syncthreads();
#pragma unroll
  for (int r = r0; r < 32; r += 8)
    outp[(size_t)(by + r) * DMODEL + bx + c] = f2b(tile[c][r]);
}

// ---------------- router + beta/g small projections: one wave per token ----------------
__global__ __launch_bounds__(64) void router_kernel(
    const float* __restrict__ h, const float* __restrict__ Wb,
    const float* __restrict__ Wa, const float* __restrict__ Wgate,
    const float* __restrict__ A_log, const float* __restrict__ dt_bias,
    float* __restrict__ beta_o, float* __restrict__ g_o, float* __restrict__ w_o) {
  const int t = blockIdx.x;
  const int lane = threadIdx.x;
  float hv[8];
#pragma unroll
  for (int j = 0; j < 8; ++j) hv[j] = h[(size_t)t * DMODEL + j * 64 + lane];
  float db[8], da[8], dg[4];
#pragma unroll
  for (int c = 0; c < 8; ++c) {
    float s1 = 0.f, s2 = 0.f;
#pragma unroll
    for (int j = 0; j < 8; ++j) {
      int row = j * 64 + lane;
      s1 += hv[j] * Wb[row * NHEADS + c];
      s2 += hv[j] * Wa[row * NHEADS + c];
    }
#pragma unroll
    for (int off = 1; off < 64; off <<= 1) {
      s1 += __shfl_xor(s1, off);
      s2 += __shfl_xor(s2, off);
    }
    db[c] = s1; da[c] = s2;
  }
#pragma unroll
  for (int c = 0; c < 4; ++c) {
    float s = 0.f;
#pragma unroll
    for (int j = 0; j < 8; ++j) s += hv[j] * Wgate[(j * 64 + lane) * NEXP + c];
#pragma unroll
    for (int off = 1; off < 64; off <<= 1) s += __shfl_xor(s, off);
    dg[c] = s;
  }
  if (lane == 0) {
#pragma unroll
    for (int c = 0; c < 8; ++c) {
      beta_o[t * NHEADS + c] = dev_sigmoid(db[c]);
      g_o[t * NHEADS + c] = -expf(A_log[c]) * dev_softplus(da[c] + dt_bias[c]);
    }
    // softmax over 4 experts (max-subtracted, like jax.nn.softmax)
    float mx = fmaxf(fmaxf(dg[0], dg[1]), fmaxf(dg[2], dg[3]));
    float p[4]; float sum = 0.f;
#pragma unroll
    for (int c = 0; c < 4; ++c) { p[c] = expf(dg[c] - mx); sum += p[c]; }
#pragma unroll
    for (int c = 0; c < 4; ++c) p[c] /= sum;
    // top-2, first-occurrence tie-break (matches jax.lax.top_k)
    float v1 = -1e30f; int i1 = 0;
#pragma unroll
    for (int c = 0; c < 4; ++c) { if (p[c] > v1) { v1 = p[c]; i1 = c; } }
    float v2 = -1e30f; int i2 = -1;
#pragma unroll
    for (int c = 0; c < 4; ++c) { if (c != i1 && p[c] > v2) { v2 = p[c]; i2 = c; } }
    float s2v = v1 + v2;
#pragma unroll
    for (int c = 0; c < 4; ++c) {
      float wv = 0.f;
      if (c == i1) wv = v1 / s2v;
      else if (c == i2) wv = v2 / s2v;
      w_o[t * NEXP + c] = wv;
    }
  }
}

// ---------------- routed-token compaction: one wave per (e,b) ----------------
__global__ __launch_bounds__(64) void compact_kernel(
    const float* __restrict__ wbuf, int* __restrict__ tidx, int* __restrict__ tcnt) {
  const int e = blockIdx.x, b = blockIdx.y;
  const int lane = threadIdx.x;
  int* out = tidx + (e * BATCH + b) * SEQ;
  int cnt = 0;
  for (int g0 = 0; g0 < SEQ; g0 += 64) {
    const int l = g0 + lane;
    const float w = wbuf[(b * SEQ + l) * NEXP + e];
    const unsigned long long m = __ballot(w > 0.f);
    const int pos = __popcll(m & ((1ull << lane) - 1ull));
    if (w > 0.f) out[cnt + pos] = l;
    cnt += __popcll(m);
  }
  if (lane == 0) tcnt[e * BATCH + b] = cnt;
}

// ---------------- bf16 MFMA GEMM: C[M,512] = A(bf16)[M,512] @ B(bf16,[n][k]) ---------
// Block: 128 threads (2 waves), tile 128(M) x 64(N), BK = 32.
// MODE 0: plain fp32 out  MODE 1: silu  MODE 2: silu + per-64-col-head l2norm
#define LDA 56  // padded LDS row stride in shorts (112 B: 16B-aligned, bank-spread)
template <int MODE>
__global__ __launch_bounds__(128) void gemm_mfma(
    const u16* __restrict__ A, const u16* __restrict__ Bt,
    float* __restrict__ C) {
  constexpr int K = DMODEL, N = DMODEL;
  __shared__ __align__(16) short As[128 * LDA];
  __shared__ __align__(16) short Bs[64 * LDA];
  const int tid = threadIdx.x;
  const int wave = tid >> 6, lane = tid & 63;
  const int quad = lane >> 4, l16 = lane & 15;
  const int m0 = blockIdx.x * 128, n0 = blockIdx.y * 64;

  // staging: A row = tid (128 rows x 32 k); B rows: 2 threads per n-row, 16 k each
  const int bn = tid >> 1, bk = (tid & 1) * 16;
  const u16* Abase = A + (size_t)(m0 + tid) * K;
  const u16* Bbase = Bt + (size_t)(n0 + bn) * K + bk;

  f32x4 acc[4][4];
#pragma unroll
  for (int i = 0; i < 4; ++i)
#pragma unroll
    for (int j = 0; j < 4; ++j) acc[i][j] = (f32x4){0.f, 0.f, 0.f, 0.f};

  int4 pa0, pa1, pa2, pa3, pb0, pb1;
  {
    const u16* p = Abase;
    pa0 = *(const int4*)p; pa1 = *(const int4*)(p + 8);
    pa2 = *(const int4*)(p + 16); pa3 = *(const int4*)(p + 24);
    const u16* q = Bbase;
    pb0 = *(const int4*)q; pb1 = *(const int4*)(q + 8);
  }

  for (int kk = 0; kk < K; kk += 32) {
    __syncthreads();
    *(int4*)&As[tid * LDA + 0] = pa0;
    *(int4*)&As[tid * LDA + 8] = pa1;
    *(int4*)&As[tid * LDA + 16] = pa2;
    *(int4*)&As[tid * LDA + 24] = pa3;
    *(int4*)&Bs[bn * LDA + bk] = pb0;
    *(int4*)&Bs[bn * LDA + bk + 8] = pb1;
    __syncthreads();
    if (kk + 32 < K) {
      const u16* p = Abase + kk + 32;
      pa0 = *(const int4*)p; pa1 = *(const int4*)(p + 8);
      pa2 = *(const int4*)(p + 16); pa3 = *(const int4*)(p + 24);
      const u16* q = Bbase + kk + 32;
      pb0 = *(const int4*)q; pb1 = *(const int4*)(q + 8);
    }
    bf16x8 af[4], bfg[4];
#pragma unroll
    for (int mi = 0; mi < 4; ++mi)
      af[mi] = *(const bf16x8*)&As[(wave * 64 + mi * 16 + l16) * LDA + quad * 8];
#pragma unroll
    for (int ni = 0; ni < 4; ++ni)
      bfg[ni] = *(const bf16x8*)&Bs[(ni * 16 + l16) * LDA + quad * 8];
#pragma unroll
    for (int mi = 0; mi < 4; ++mi)
#pragma unroll
      for (int ni = 0; ni < 4; ++ni)
        acc[mi][ni] = __builtin_amdgcn_mfma_f32_16x16x32_bf16(af[mi], bfg[ni],
                                                              acc[mi][ni], 0, 0, 0);
  }

  // epilogue: C/D layout col = lane&15 (within 16-subtile), row = quad*4 + r
#pragma unroll
  for (int mi = 0; mi < 4; ++mi) {
#pragma unroll
    for (int r = 0; r < 4; ++r) {
      const int row = m0 + wave * 64 + mi * 16 + quad * 4 + r;
      float s[4];
#pragma unroll
      for (int ni = 0; ni < 4; ++ni) {
        float x = acc[mi][ni][r];
        s[ni] = (MODE == 0) ? x : dev_silu(x);
      }
      if (MODE == 2) {
        float ss = s[0] * s[0] + s[1] * s[1] + s[2] * s[2] + s[3] * s[3];
        ss += __shfl_xor(ss, 1);
        ss += __shfl_xor(ss, 2);
        ss += __shfl_xor(ss, 4);
        ss += __shfl_xor(ss, 8);
        const float rn = 1.0f / sqrtf(ss + 1e-6f);
#pragma unroll
        for (int ni = 0; ni < 4; ++ni) s[ni] *= rn;
      }
#pragma unroll
      for (int ni = 0; ni < 4; ++ni)
        C[(size_t)row * N + n0 + ni * 16 + l16] = s[ni];
    }
  }
}

// ---------------- gated delta-rule scan (R3-proven variant) ----------------
// grid (NEXP*2, BATCH, NHEADS); ONE WAVE per block. Compact token list,
// depth-3 pipeline over mod-4 rotating slots, 4 LDS broadcast buffers.
__global__ __launch_bounds__(64) void scan_kernel(
    const float* __restrict__ qb, const float* __restrict__ kb,
    const float* __restrict__ vb, const float* __restrict__ betab,
    const float* __restrict__ gbuf, const float* __restrict__ wbuf,
    const int* __restrict__ tidx, const int* __restrict__ tcnt,
    float* __restrict__ coreb) {
  const int vhalf = blockIdx.x & 1, e = blockIdx.x >> 1;
  const int b = blockIdx.y, hh = blockIdx.z;
  const int lane = threadIdx.x;
  const int kh = lane >> 5;
  const int vi = lane & 31;
  const int cv = vhalf * 32 + vi;
  const int* idx = tidx + (e * BATCH + b) * SEQ;
  const int n = tcnt[e * BATCH + b];
  if (n == 0) return;
  const int nm1 = n - 1;

  __shared__ __align__(16) float lk[4][64];
  __shared__ __align__(16) float lq[4][64];
  __shared__ int lidx[SEQ];

  for (int i = lane; i < SEQ; i += 64) lidx[i] = idx[i < n ? i : nm1];
  __syncthreads();

  v2f S2[16];
#pragma unroll
  for (int j = 0; j < 16; ++j) S2[j] = (v2f){0.f, 0.f};

  float kf[4], qf[4], vf[4], gf[4], bf[4], wf[4], egr[4];
  int tcur[4], tok4[4];

#define PREF(SLOT, TK)                                          \
  do {                                                          \
    const int tn_ = b * SEQ + (TK);                             \
    const size_t kq_ = (size_t)tn_ * DMODEL + hh * 64 + lane;   \
    kf[SLOT] = kb[kq_];                                         \
    qf[SLOT] = qb[kq_];                                         \
    vf[SLOT] = vb[(size_t)tn_ * DMODEL + hh * 64 + cv];         \
    gf[SLOT] = gbuf[tn_ * NHEADS + hh];                         \
    bf[SLOT] = betab[tn_ * NHEADS + hh];                        \
    wf[SLOT] = wbuf[tn_ * NEXP + e];                            \
    tcur[SLOT] = tn_;                                           \
  } while (0)

  tok4[0] = lidx[0];
  tok4[1] = lidx[1 < n ? 1 : nm1];
  tok4[2] = lidx[2 < n ? 2 : nm1];
  tok4[3] = lidx[3 < n ? 3 : nm1];
  PREF(0, tok4[0]);
  PREF(1, tok4[1]);
  PREF(2, tok4[2]);
  lk[0][lane] = kf[0];
  lq[0][lane] = qf[0];
  egr[0] = expf(gf[0]);

  const int m = (n + 3) & ~3;
  for (int i = 0; i < m; i += 4) {
#pragma unroll
    for (int u = 0; u < 4; ++u) {
      const int s = i + u;
      const int sN = (u + 3) & 3;
      const int s1 = (u + 1) & 3;
      PREF(sN, tok4[sN]);
      int a4 = s + 4;
      a4 = a4 < nm1 ? a4 : nm1;
      tok4[u] = lidx[a4];
      __builtin_amdgcn_wave_barrier();
      lk[s1][lane] = kf[s1];
      lq[s1][lane] = qf[s1];
      __builtin_amdgcn_wave_barrier();
      egr[s1] = expf(gf[s1]);
      const v4f* lk4 = (const v4f*)&lk[u][kh * 32];
      const v4f* lq4 = (const v4f*)&lq[u][kh * 32];
      v2f myk[16];
      v2f c0 = (v2f){0.f, 0.f}, c1 = c0, c2 = c0, c3 = c0;
#pragma unroll
      for (int j = 0; j < 8; ++j) {
        const v4f k4 = lk4[j];
        const v2f klo = (v2f){k4.x, k4.y};
        const v2f khi = (v2f){k4.z, k4.w};
        myk[2 * j] = klo; myk[2 * j + 1] = khi;
        if (j & 1) {
          c2 = __builtin_elementwise_fma(klo, S2[2 * j], c2);
          c3 = __builtin_elementwise_fma(khi, S2[2 * j + 1], c3);
        } else {
          c0 = __builtin_elementwise_fma(klo, S2[2 * j], c0);
          c1 = __builtin_elementwise_fma(khi, S2[2 * j + 1], c1);
        }
      }
      const v2f cacc = (c0 + c1) + (c2 + c3);
      float c = cacc.x + cacc.y;
      c += __shfl_xor(c, 32);
      const float egc = egr[u];
      const float delta = (vf[u] - egc * c) * bf[u];
      const v2f d2 = (v2f){delta, delta};
      const v2f eg2 = (v2f){egc, egc};
      v2f o0 = (v2f){0.f, 0.f}, o1 = o0, o2 = o0, o3 = o0;
#pragma unroll
      for (int j = 0; j < 8; ++j) {
        const v4f q4 = lq4[j];
        const v2f qlo = (v2f){q4.x, q4.y};
        const v2f qhi = (v2f){q4.z, q4.w};
        const v2f s0 = __builtin_elementwise_fma(S2[2 * j], eg2, myk[2 * j] * d2);
        const v2f s1v = __builtin_elementwise_fma(S2[2 * j + 1], eg2, myk[2 * j + 1] * d2);
        S2[2 * j] = s0; S2[2 * j + 1] = s1v;
        if (j & 1) {
          o2 = __builtin_elementwise_fma(qlo, s0, o2);
          o3 = __builtin_elementwise_fma(qhi, s1v, o3);
        } else {
          o0 = __builtin_elementwise_fma(qlo, s0, o0);
          o1 = __builtin_elementwise_fma(qhi, s1v, o1);
        }
      }
      const v2f oacc = (o0 + o1) + (o2 + o3);
      float o = oacc.x + oacc.y;
      o += __shfl_xor(o, 32);
      if (kh == 0 && s < n)
        atomicAdd(&coreb[(size_t)tcur[u] * DMODEL + hh * 64 + cv],
                  o * 0.125f * wf[u]);
    }
  }
#undef PREF
}

// ---------------- fused gated RMSNorm -> bf16: one wave per (token, head) ------------
__global__ __launch_bounds__(512) void rmsnorm_kernel(
    const float* __restrict__ coreb, const float* __restrict__ gateb,
    const float* __restrict__ wn, u16* __restrict__ outb) {
  const int t = blockIdx.x;
  const int tid = threadIdx.x;  // 512 = 8 heads * 64; wave == head
  const int v = tid & 63;
  const float x = coreb[(size_t)t * DMODEL + tid];
  float ss = x * x;
#pragma unroll
  for (int off = 1; off < 64; off <<= 1) ss += __shfl_xor(ss, off);
  const float r = rsqrtf(ss * (1.0f / 64.0f) + 1e-5f);
  const float gt = gateb[(size_t)t * DMODEL + tid];  // already silu'd
  outb[(size_t)t * DMODEL + tid] = f2b(x * r * wn[v] * gt);
}

extern "C" void kernel_launch(void* const* d_in, const int* in_sizes, int n_in,
                              void* d_out, int out_size, void* d_ws, size_t ws_size,
                              hipStream_t stream) {
  const float* h       = (const float*)d_in[0];
  const float* Wq      = (const float*)d_in[1];
  const float* Wgate   = (const float*)d_in[2];
  const float* Wk      = (const float*)d_in[3];
  const float* Wv      = (const float*)d_in[4];
  const float* Wb      = (const float*)d_in[5];
  const float* Wa      = (const float*)d_in[6];
  const float* A_log   = (const float*)d_in[7];
  const float* dt_bias = (const float*)d_in[8];
  const float* Wg      = (const float*)d_in[9];
  const float* wn      = (const float*)d_in[10];
  const float* Wo      = (const float*)d_in[11];
  float* out = (float*)d_out;

  char* ws = (char*)d_ws;
  const size_t big = (size_t)NTOK * DMODEL;  // 2M elements
  float* qb    = (float*)ws;                    ws += big * 4;
  float* kb    = (float*)ws;                    ws += big * 4;
  float* vb    = (float*)ws;                    ws += big * 4;
  float* gateb = (float*)ws;                    ws += big * 4;
  float* coreb = (float*)ws;                    ws += big * 4;
  float* betab = (float*)ws;                    ws += (size_t)NTOK * NHEADS * 4;
  float* gbuf  = (float*)ws;                    ws += (size_t)NTOK * NHEADS * 4;
  float* wbuf  = (float*)ws;                    ws += (size_t)NTOK * NEXP * 4;
  int*   tidx  = (int*)ws;                      ws += (size_t)NEXP * BATCH * SEQ * 4;
  int*   tcnt  = (int*)ws;                      ws += 64;
  u16*   hb    = (u16*)ws;                      ws += big * 2;          // bf16 h
  u16*   nb    = (u16*)ws;                      ws += big * 2;          // bf16 normed
  u16*   wtq   = (u16*)ws;                      ws += (size_t)DMODEL * DMODEL * 2;
  u16*   wtk   = (u16*)ws;                      ws += (size_t)DMODEL * DMODEL * 2;
  u16*   wtv   = (u16*)ws;                      ws += (size_t)DMODEL * DMODEL * 2;
  u16*   wtg   = (u16*)ws;                      ws += (size_t)DMODEL * DMODEL * 2;
  u16*   wto   = (u16*)ws;                      ws += (size_t)DMODEL * DMODEL * 2;

  // zero the core accumulator (ws is poisoned before every timed launch)
  zero_kernel<<<dim3(NTOK * DMODEL / 4 / 256), 256, 0, stream>>>((float4*)coreb);

  // casts
  cast_h_kernel<<<dim3(big / 4 / 256), 256, 0, stream>>>((const float4*)h, (ushort4*)hb);
  dim3 tg(16, 16);
  castT_kernel<<<tg, 256, 0, stream>>>(Wq, wtq);
  castT_kernel<<<tg, 256, 0, stream>>>(Wk, wtk);
  castT_kernel<<<tg, 256, 0, stream>>>(Wv, wtv);
  castT_kernel<<<tg, 256, 0, stream>>>(Wg, wtg);
  castT_kernel<<<tg, 256, 0, stream>>>(Wo, wto);

  router_kernel<<<dim3(NTOK), 64, 0, stream>>>(h, Wb, Wa, Wgate, A_log, dt_bias,
                                               betab, gbuf, wbuf);
  compact_kernel<<<dim3(NEXP, BATCH), 64, 0, stream>>>(wbuf, tidx, tcnt);

  dim3 gg(NTOK / 128, DMODEL / 64);
  gemm_mfma<2><<<gg, 128, 0, stream>>>(hb, wtq, qb);
  gemm_mfma<2><<<gg, 128, 0, stream>>>(hb, wtk, kb);
  gemm_mfma<1><<<gg, 128, 0, stream>>>(hb, wtv, vb);
  gemm_mfma<1><<<gg, 128, 0, stream>>>(hb, wtg, gateb);

  scan_kernel<<<dim3(NEXP * 2, BATCH, NHEADS), 64, 0, stream>>>(
      qb, kb, vb, betab, gbuf, wbuf, tidx, tcnt, coreb);

  rmsnorm_kernel<<<dim3(NTOK), 512, 0, stream>>>(coreb, gateb, wn, nb);

  gemm_mfma<0><<<gg, 128, 0, stream>>>(nb, wto, out);
}